// Round 1
// 281.070 us; speedup vs baseline: 1.0656x; 1.0656x over previous
//
#include <hip/hip_runtime.h>

// GlobalFilter (GFNet): out = irfft2(rfft2(x)·W, ortho) == per-channel 16x16
// circular convolution with k[:,:,c] = inverse transform of W. ortho norms cancel.
//
// Lessons:
//  R1: k from global -> exposed L2 latency (k reads are a per-lane gather; k
//      MUST stay in LDS).
//  R2: lane-varying LDS x-column -> bank conflicts; dynamic reg-array index
//      -> scratch. NEVER index a register array with a runtime value.
//  R3: conditionals in hot unrolled loops -> spill. Keep the loop body
//      conditional-free (redundant qq=15 prefetch instead of an if).
//  R4 (300 us): both full tiles in LDS = 64 KB -> 2 blocks/CU -> 1 wave/SIMD.
//      VALUBusy 50%: every per-qq kv[16] LDS burst is an unhidden stall.
//  R5 (this version): x column j=(-qq)&15 is consumed exactly once -> full
//      32 KB x tile had ZERO temporal reuse. Stream it: 2 KB column,
//      double-buffered, prefetched one qq ahead with global_load_lds (dest is
//      lane-linear: wave-uniform base + lane*16, per HW constraint). LDS drops
//      to 48 KB; fuse 2 batches/block (shared ks) -> 3 blocks/CU = 3 waves/SIMD.
//      kv-burst latency now hides under other waves' FMA streams.

constexpr int PP = 16;   // patch size
constexpr int NS = 256;  // PP*PP spatial
constexpr int CH = 768;  // channels
constexpr int NB = 128;  // batch

// async global->LDS, 16B per lane. lds ptr must be wave-uniform base; HW adds
// lane*16. Source address is per-lane.
__device__ __forceinline__ void cp_g2s_16(const void* g, void* s) {
    __builtin_amdgcn_global_load_lds(
        (const __attribute__((address_space(1))) void*)g,
        (__attribute__((address_space(3))) void*)s, 16, 0, 0);
}

// ---------------- Kernel A: build real conv kernel k[p*16+q][c] -------------
__global__ void gf_build_k(const float* __restrict__ w, float* __restrict__ kbuf) {
    __shared__ float ct[16], st[16];
    if (threadIdx.x < 16) {
        const float ang = 6.28318530717958647692f * (float)threadIdx.x * (1.0f / 16.0f);
        ct[threadIdx.x] = cosf(ang);
        st[threadIdx.x] = sinf(ang);
    }
    __syncthreads();

    const int pq = blockIdx.x;                              // 0..255
    const int c  = blockIdx.y * blockDim.x + threadIdx.x;   // 0..767
    const int p = pq >> 4, q = pq & 15;

    float acc = 0.0f;
#pragma unroll 1
    for (int u = 0; u < 16; ++u) {
        const float* wu = w + (size_t)(u * 9) * 2 * CH + 2 * c;
#pragma unroll
        for (int v = 0; v < 9; ++v) {
            const float cv = (v == 0 || v == 8) ? 1.0f : 2.0f;
            const int t = (u * p + v * q) & 15;  // lane-uniform -> LDS broadcast
            const float wr = wu[(size_t)v * 2 * CH];
            const float wi = wu[(size_t)v * 2 * CH + 1];
            acc += cv * (wr * ct[t] - wi * st[t]);
        }
    }
    kbuf[pq * CH + c] = acc * (1.0f / 256.0f);
}

// ---------------- Kernel B: depthwise 16x16 circular conv -------------------
// block = 256 threads = 2 batches x (8 ch-groups x 16 n-cols). 48 KB LDS:
//   ks[256][32]          32 KB  (shared by both batch halves)
//   xcol[2][2][16][32]   16 KB  (double-buffered x column per batch half)
// 3 blocks/CU -> 12 waves/CU (3/SIMD).
__global__ __launch_bounds__(256, 3) void gf_conv(const float* __restrict__ x,
                                                  const float* __restrict__ kbuf,
                                                  float* __restrict__ out) {
    __shared__ __align__(16) float ks[NS][32];
    __shared__ __align__(16) float xcol[2][2][16][32];  // [buf][half][d][ch]

    const int tid  = threadIdx.x;
    const int half = tid >> 7;                 // batch half 0/1
    const int b    = (blockIdx.y << 1) | half;
    const int c0   = blockIdx.x * 32;
    const int wave = tid >> 6;                 // 0..3 (wave-uniform)
    const int idx  = tid & 127;                // id within batch half
    const int dr   = idx >> 3;                 // stage row 0..15
    const int ch4  = (idx & 7) << 2;           // stage chan offset (floats)

    const float* xb = x + (size_t)b * NS * CH + c0;

    // ---- stage k tile: 8 x global_load_lds per thread, lane-linear dest.
    // wave w, instr i covers ks bytes [i*4096 + w*1024, +1024):
    //   s = i*32 + (tid>>3), ch = (tid&7)*4  (matches lds flat offset)
    {
        const int srow = tid >> 3;             // 0..31
        const int kch4 = (tid & 7) << 2;
        const float* kb = kbuf + c0;
        float* lbase = &ks[0][0] + wave * 256; // 1 KB per wave, uniform
#pragma unroll
        for (int i = 0; i < 8; ++i)
            cp_g2s_16(kb + (size_t)(i * 32 + srow) * CH + kch4, lbase + i * 1024);
    }
    // ---- stage x column j(0)=0 into buf 0
    {
        float* lbase = &xcol[0][half][0][0] + (wave & 1) * 256;  // uniform
        cp_g2s_16(xb + (size_t)(dr * 16 + 0) * CH + ch4, lbase);
    }
    __syncthreads();  // drains vmcnt(0): all staging landed

    const int chq = (tid & 7) << 2;   // channel float4 within tile
    const int n   = (tid >> 3) & 15;  // output column 0..15

    float4 acc[16];
#pragma unroll
    for (int m = 0; m < 16; ++m) acc[m] = make_float4(0.f, 0.f, 0.f, 0.f);

#pragma unroll 1
    for (int qq = 0; qq < 16; ++qq) {
        // prefetch next column j(qq+1) = (15-qq)&15 into buf[(qq+1)&1].
        // (qq=15: redundant reload of col 0 -> branch-free loop body, R3)
        {
            float* lbase = &xcol[(qq + 1) & 1][half][0][0] + (wave & 1) * 256;
            cp_g2s_16(xb + (size_t)(dr * 16 + ((15 - qq) & 15)) * CH + ch4, lbase);
        }

        const int q = (qq + n) & 15;  // lane-varying k column
        const float4* xrow = (const float4*)&xcol[qq & 1][half][0][chq];

        // kv[16]: distinct-address b128 LDS reads (conflict-free, measured 0)
        float4 kv[16];
#pragma unroll
        for (int p = 0; p < 16; ++p)
            kv[p] = *(const float4*)&ks[(p << 4) | q][chq];

        // d = (m - p) & 15: one broadcast x row per d, all indices static
#pragma unroll
        for (int d = 0; d < 16; ++d) {
            const float4 xx = xrow[d * 8];  // row stride = 32 floats = 8 float4
#pragma unroll
            for (int p = 0; p < 16; ++p) {
                const int m = (p + d) & 15;  // compile-time
                acc[m].x = fmaf(kv[p].x, xx.x, acc[m].x);
                acc[m].y = fmaf(kv[p].y, xx.y, acc[m].y);
                acc[m].z = fmaf(kv[p].z, xx.z, acc[m].z);
                acc[m].w = fmaf(kv[p].w, xx.w, acc[m].w);
            }
        }
        // drains the prefetch (vmcnt) and orders buffer reuse across waves
        __syncthreads();
    }

    float* ob = out + (size_t)b * NS * CH + c0 + chq;
#pragma unroll
    for (int m = 0; m < 16; ++m)
        *(float4*)(ob + (size_t)((m << 4) + n) * CH) = acc[m];
}

// ---------------------------------------------------------------------------
extern "C" void kernel_launch(void* const* d_in, const int* in_sizes, int n_in,
                              void* d_out, int out_size, void* d_ws, size_t ws_size,
                              hipStream_t stream) {
    const float* x = (const float*)d_in[0];        // [128, 256, 768] fp32
    const float* w = (const float*)d_in[1];        // [16, 9, 768, 2] fp32
    float* out  = (float*)d_out;                   // [128, 256, 768] fp32
    float* kbuf = (float*)d_ws;                    // 256*768 fp32 = 768 KB

    gf_build_k<<<dim3(256, 3), 256, 0, stream>>>(w, kbuf);
    gf_conv<<<dim3(CH / 32, NB / 2), 256, 0, stream>>>(x, kbuf, out);
}